// Round 2
// baseline (24243.510 us; speedup 1.0000x reference)
//
#include <hip/hip_runtime.h>
#include <math.h>

// Dims: B=128, T=256, D=512, F0=2048, F1=1024, R=B*T=32768
//
// ws layout (float index offsets):
//  e0     @ 0          16777216   emb0 out (t-major: row = t*128+b) -> later g0
//  e1     @ 16777216   16777216   emb1 out -> later g1
//  H0     @ 33554432   16842752   (257 slots * 65536) h0 history, slot0 = 0
//  H1     @ 50397184   16842752
//  cbuf   @ 67239936   131072     c state, both cells
//  psum   @ 67371008   65536
//  psq    @ 67436544   65536
//  mean   @ 67502080   512
//  scale  @ 67502592   512
//  -- bf16 (ushort) planes below, sizes given in float-equivalents --
//  wr0hi  @ 67503104   1048576    permuted+concat [2048][1024] cell0 hi
//  wr0lo  @ 68551680   1048576
//  wr1hi  @ 69600256   1048576
//  wr1lo  @ 70648832   1048576
//  bc0    @ 71697408   2048       permuted combined bias (fp32)
//  bc1    @ 71699456   2048
//  we0hi  @ 71701504   524288     [512][2048]
//  we0lo  @ 72225792   524288
//  we1hi  @ 72750080   262144     [512][1024]
//  we1lo  @ 73012224   262144
//  wg0hi  @ 73274368   131072     [512][512]
//  wg0lo  @ 73405440   131072
//  wg1hi  @ 73536512   131072
//  wg1lo  @ 73667584   131072
//  wf1hi  @ 73798656   131072
//  wf1lo  @ 73929728   131072
//  wf2hi  @ 74060800   131072
//  wf2lo  @ 74191872   131072
//  end    @ 74322944 floats  (~298 MB)

typedef short s16x8 __attribute__((ext_vector_type(8)));
typedef float f32x4 __attribute__((ext_vector_type(4)));
typedef unsigned short u16;

__device__ __forceinline__ float sigmoidf_(float x){ return 1.0f/(1.0f+expf(-x)); }

__device__ __forceinline__ u16 f2bf(float x){
  unsigned int u = __float_as_uint(x);
  unsigned int r = u + 0x7fffu + ((u>>16)&1u);
  return (u16)(r>>16);
}
__device__ __forceinline__ float bf2f(u16 s){ return __uint_as_float(((unsigned int)s)<<16); }

// ---------------- weight splitting -------------------------------------------
__global__ __launch_bounds__(256) void split_plain(const float* __restrict__ src,
                                                   u16* __restrict__ hi, u16* __restrict__ lo, int n)
{
  int i = blockIdx.x*256 + threadIdx.x;
  if (i < n){
    float v = src[i];
    u16 h = f2bf(v);
    hi[i] = h;
    lo[i] = f2bf(v - bf2f(h));
  }
}

// permute LSTM weight rows (n' = d*4+q from row q*512+d) and concat ih|hh along K
__global__ __launch_bounds__(256) void split_gates(const float* __restrict__ wih,
                                                   const float* __restrict__ whh,
                                                   const float* __restrict__ bih,
                                                   const float* __restrict__ bhh,
                                                   u16* __restrict__ hi, u16* __restrict__ lo,
                                                   float* __restrict__ bc)
{
  int np = blockIdx.x;              // 0..2047 permuted row
  int d = np>>2, q = np&3;
  int orow = q*512 + d;
  for (int k = threadIdx.x; k < 1024; k += 256){
    float v = (k < 512) ? wih[(size_t)orow*512 + k] : whh[(size_t)orow*512 + (k-512)];
    u16 h = f2bf(v);
    hi[(size_t)np*1024 + k] = h;
    lo[(size_t)np*1024 + k] = f2bf(v - bf2f(h));
  }
  if (threadIdx.x == 0) bc[np] = bih[orow] + bhh[orow];
}

// ---------------- split-bf16 MFMA GEMM: C = A @ W^T (+epilogues) --------------
// A fp32 MxK (split in-kernel), W pre-split bf16 hi/lo [512][K]. N fixed 512.
// Tiles 128x128, 4 waves of 64x64, BK=32, 3 MFMA passes (hihi, hilo, lohi).
// MODE 0: out[t*128+b][n] = acc + bias[n]           (A rows r=b*256+t; emb)
// MODE 1: out[r][n] = sigmoid(acc+bias[n])*other[r][n]
// MODE 2: dual pair; out[b*256+t][n] = tanh(acc+bias[n])  (A rows r=t*128+b)
template<int MODE>
__global__ __launch_bounds__(256) void gemm_sp(
    const float* __restrict__ A, const u16* __restrict__ Whi, const u16* __restrict__ Wlo,
    const float* __restrict__ A2, const u16* __restrict__ W2hi, const u16* __restrict__ W2lo,
    const float* __restrict__ bias, const float* __restrict__ other,
    float* __restrict__ out, int K)
{
  __shared__ u16 Ah[128][40];
  __shared__ u16 Al[128][40];
  __shared__ u16 Wh[128][40];
  __shared__ u16 Wl[128][40];

  int bx = blockIdx.x;
  int nt = bx & 3, mt = bx >> 2;
  int m0 = mt*128, n0 = nt*128;
  int tid = threadIdx.x, lane = tid & 63, w = tid >> 6;
  int wm = (w>>1)*64, wn = (w&1)*64;

  f32x4 acc[4][4];
  #pragma unroll
  for (int i=0;i<4;i++)
    #pragma unroll
    for (int j=0;j<4;j++) acc[i][j] = (f32x4){0.f,0.f,0.f,0.f};

  const int npair = (MODE==2) ? 2 : 1;
  for (int pair=0; pair<npair; ++pair){
    const float* __restrict__ Ap = pair ? A2 : A;
    const u16* __restrict__ Wph = pair ? W2hi : Whi;
    const u16* __restrict__ Wpl = pair ? W2lo : Wlo;
    for (int k0=0; k0<K; k0+=32){
      // stage A (128x32 fp32 -> hi/lo)
      #pragma unroll
      for (int p=0;p<4;p++){
        int fi = p*256 + tid;
        int r = fi>>3, c = fi&7;
        float4 v = *(const float4*)&Ap[(size_t)(m0+r)*K + k0 + c*4];
        u16 h0=f2bf(v.x), h1=f2bf(v.y), h2=f2bf(v.z), h3=f2bf(v.w);
        u16 l0=f2bf(v.x-bf2f(h0)), l1=f2bf(v.y-bf2f(h1)), l2=f2bf(v.z-bf2f(h2)), l3=f2bf(v.w-bf2f(h3));
        uint2 ph = { (unsigned)h0 | ((unsigned)h1<<16), (unsigned)h2 | ((unsigned)h3<<16) };
        uint2 pl = { (unsigned)l0 | ((unsigned)l1<<16), (unsigned)l2 | ((unsigned)l3<<16) };
        *(uint2*)&Ah[r][c*4] = ph;
        *(uint2*)&Al[r][c*4] = pl;
      }
      // stage W (128x32 bf16 hi/lo, direct copy)
      #pragma unroll
      for (int p=0;p<2;p++){
        int fi = p*256 + tid;
        int r = fi>>2, c = fi&3;
        uint4 vh = *(const uint4*)&Wph[(size_t)(n0+r)*K + k0 + c*8];
        uint4 vl = *(const uint4*)&Wpl[(size_t)(n0+r)*K + k0 + c*8];
        *(uint4*)&Wh[r][c*8] = vh;
        *(uint4*)&Wl[r][c*8] = vl;
      }
      __syncthreads();
      s16x8 ah[4], al[4];
      #pragma unroll
      for (int mf=0;mf<4;mf++){
        ah[mf] = *(const s16x8*)&Ah[wm + mf*16 + (lane&15)][(lane>>4)*8];
        al[mf] = *(const s16x8*)&Al[wm + mf*16 + (lane&15)][(lane>>4)*8];
      }
      #pragma unroll
      for (int nf=0;nf<4;nf++){
        s16x8 wh = *(const s16x8*)&Wh[wn + nf*16 + (lane&15)][(lane>>4)*8];
        s16x8 wl = *(const s16x8*)&Wl[wn + nf*16 + (lane&15)][(lane>>4)*8];
        #pragma unroll
        for (int mf=0;mf<4;mf++){
          acc[mf][nf] = __builtin_amdgcn_mfma_f32_16x16x32_bf16(ah[mf], wh, acc[mf][nf], 0,0,0);
          acc[mf][nf] = __builtin_amdgcn_mfma_f32_16x16x32_bf16(ah[mf], wl, acc[mf][nf], 0,0,0);
          acc[mf][nf] = __builtin_amdgcn_mfma_f32_16x16x32_bf16(al[mf], wh, acc[mf][nf], 0,0,0);
        }
      }
      __syncthreads();
    }
  }
  // epilogue: C/D frag layout col=lane&15, row=(lane>>4)*4+reg
  #pragma unroll
  for (int mf=0;mf<4;mf++){
    #pragma unroll
    for (int nf=0;nf<4;nf++){
      int col = n0 + wn + nf*16 + (lane&15);
      int row0 = m0 + wm + mf*16 + (lane>>4)*4;
      float b = bias[col];
      f32x4 a = acc[mf][nf];
      #pragma unroll
      for (int g=0; g<4; ++g){
        int r = row0 + g;
        float v = a[g] + b;
        size_t orow;
        if (MODE==0){
          orow = (size_t)((r & 255)*128 + (r>>8));
        } else if (MODE==1){
          v = sigmoidf_(v) * other[(size_t)r*512 + col];
          orow = (size_t)r;
        } else {
          v = tanhf(v);
          orow = (size_t)((r & 127)*256 + (r>>7));
        }
        out[orow*512 + col] = v;
      }
    }
  }
}

// ---------------- BN stats & apply --------------------------------------------
__global__ __launch_bounds__(256) void bn_stats1(const float* __restrict__ Y,
                                                 float* __restrict__ psum,
                                                 float* __restrict__ psq)
{
  int blk = blockIdx.x;
  int tid = threadIdx.x;
  const float* base = Y + (size_t)blk*256*512;
  float sx=0.f, sy=0.f, qx=0.f, qy=0.f;
  for (int r=0;r<256;r++){
    float2 v = *(const float2*)&base[(size_t)r*512 + tid*2];
    sx += v.x; sy += v.y; qx += v.x*v.x; qy += v.y*v.y;
  }
  psum[(size_t)blk*512 + tid*2]   = sx;
  psum[(size_t)blk*512 + tid*2+1] = sy;
  psq [(size_t)blk*512 + tid*2]   = qx;
  psq [(size_t)blk*512 + tid*2+1] = qy;
}

__global__ __launch_bounds__(512) void bn_stats2(const float* __restrict__ psum,
                                                 const float* __restrict__ psq,
                                                 float* __restrict__ mean,
                                                 float* __restrict__ scale)
{
  int c = threadIdx.x;
  float s=0.f, q=0.f;
  for (int b=0;b<128;b++){ s += psum[(size_t)b*512+c]; q += psq[(size_t)b*512+c]; }
  float mu = s * (1.0f/32768.0f);
  float var = q * (1.0f/32768.0f) - mu*mu;
  mean[c] = mu;
  scale[c] = rsqrtf(var + 1e-5f);
}

__global__ __launch_bounds__(256) void bn_apply(float* __restrict__ Y,
                                                const float* __restrict__ mean,
                                                const float* __restrict__ scale,
                                                const float* __restrict__ gamma,
                                                const float* __restrict__ beta)
{
  size_t idx = (size_t)blockIdx.x*256 + threadIdx.x;
  float4 v = *(float4*)&Y[idx*4];
  int c = (int)((idx*4) & 511);
  float r[4] = {v.x,v.y,v.z,v.w};
  #pragma unroll
  for (int u=0;u<4;u++){
    float t = (r[u]-mean[c+u])*scale[c+u]*gamma[c+u]+beta[c+u];
    r[u] = fmaxf(t, 0.f);
  }
  float4 o = {r[0],r[1],r[2],r[3]};
  *(float4*)&Y[idx*4] = o;
}

// ---------------- init h_{-1}=0, c=0 -------------------------------------------
__global__ __launch_bounds__(256) void init_state(float* __restrict__ H0,
                                                  float* __restrict__ H1,
                                                  float* __restrict__ cbuf)
{
  int idx = blockIdx.x*256 + threadIdx.x;
  H0[idx] = 0.f;
  H1[idx] = 0.f;
  cbuf[idx] = 0.f;
  cbuf[idx + 65536] = 0.f;
}

// ---------------- one LSTM timestep, MFMA (both cells) --------------------------
// 64 blocks: ci = bx>>5 (cell), nt = bx&31 (64 permuted gate cols).
// A = [e_t | h_{t-1}] fp32 (split in-kernel), K=1024. W = permuted concat planes.
// 4 waves, each 32 rows x 64 cols. Epilogue: block-local pointwise c/h update.
__global__ __launch_bounds__(256) void scan_step2(
    const float* __restrict__ e0, const float* __restrict__ e1,
    const u16* __restrict__ wr0hi, const u16* __restrict__ wr0lo,
    const u16* __restrict__ wr1hi, const u16* __restrict__ wr1lo,
    const float* __restrict__ bc0, const float* __restrict__ bc1,
    const float* __restrict__ mask,
    float* __restrict__ H0, float* __restrict__ H1,
    float* __restrict__ cbuf, int t)
{
  __shared__ union {
    struct {
      u16 Ah[128][40];
      u16 Al[128][40];
      u16 Wh[64][40];
      u16 Wl[64][40];
    } s;
    float gbuf[4][32][68];
  } u;

  int bx = blockIdx.x;
  int ci = bx >> 5, nt = bx & 31;
  int n0p = nt*64;

  const float* e   = ci ? e1 : e0;
  const u16* Wrh   = ci ? wr1hi : wr0hi;
  const u16* Wrl   = ci ? wr1lo : wr0lo;
  const float* bc  = ci ? bc1 : bc0;
  float* H         = ci ? H1 : H0;

  const float* eT = e + (size_t)t*65536;
  const float* Hp = H + (size_t)t*65536;

  int tid = threadIdx.x, lane = tid & 63, w = tid >> 6;
  int wm = w*32;

  f32x4 acc[2][4];
  #pragma unroll
  for (int i=0;i<2;i++)
    #pragma unroll
    for (int j=0;j<4;j++) acc[i][j] = (f32x4){0.f,0.f,0.f,0.f};

  for (int kk=0; kk<32; ++kk){
    int k0 = kk*32;
    const float* Asrc = (kk < 16) ? eT : Hp;
    int ka = (kk < 16) ? k0 : (k0 - 512);
    // stage A
    #pragma unroll
    for (int p=0;p<4;p++){
      int fi = p*256 + tid;
      int r = fi>>3, c = fi&7;
      float4 v = *(const float4*)&Asrc[(size_t)r*512 + ka + c*4];
      u16 h0=f2bf(v.x), h1=f2bf(v.y), h2=f2bf(v.z), h3=f2bf(v.w);
      u16 l0=f2bf(v.x-bf2f(h0)), l1=f2bf(v.y-bf2f(h1)), l2=f2bf(v.z-bf2f(h2)), l3=f2bf(v.w-bf2f(h3));
      uint2 ph = { (unsigned)h0 | ((unsigned)h1<<16), (unsigned)h2 | ((unsigned)h3<<16) };
      uint2 pl = { (unsigned)l0 | ((unsigned)l1<<16), (unsigned)l2 | ((unsigned)l3<<16) };
      *(uint2*)&u.s.Ah[r][c*4] = ph;
      *(uint2*)&u.s.Al[r][c*4] = pl;
    }
    // stage W (64 rows x 32 k)
    {
      int r = tid>>2, c = tid&3;
      uint4 vh = *(const uint4*)&Wrh[(size_t)(n0p+r)*1024 + k0 + c*8];
      uint4 vl = *(const uint4*)&Wrl[(size_t)(n0p+r)*1024 + k0 + c*8];
      *(uint4*)&u.s.Wh[r][c*8] = vh;
      *(uint4*)&u.s.Wl[r][c*8] = vl;
    }
    __syncthreads();
    s16x8 ah[2], al[2];
    #pragma unroll
    for (int mf=0;mf<2;mf++){
      ah[mf] = *(const s16x8*)&u.s.Ah[wm + mf*16 + (lane&15)][(lane>>4)*8];
      al[mf] = *(const s16x8*)&u.s.Al[wm + mf*16 + (lane&15)][(lane>>4)*8];
    }
    #pragma unroll
    for (int nf=0;nf<4;nf++){
      s16x8 wh = *(const s16x8*)&u.s.Wh[nf*16 + (lane&15)][(lane>>4)*8];
      s16x8 wl = *(const s16x8*)&u.s.Wl[nf*16 + (lane&15)][(lane>>4)*8];
      #pragma unroll
      for (int mf=0;mf<2;mf++){
        acc[mf][nf] = __builtin_amdgcn_mfma_f32_16x16x32_bf16(ah[mf], wh, acc[mf][nf], 0,0,0);
        acc[mf][nf] = __builtin_amdgcn_mfma_f32_16x16x32_bf16(ah[mf], wl, acc[mf][nf], 0,0,0);
        acc[mf][nf] = __builtin_amdgcn_mfma_f32_16x16x32_bf16(al[mf], wh, acc[mf][nf], 0,0,0);
      }
    }
    __syncthreads();
  }

  // stash raw gate pre-activations into LDS (per-wave region)
  #pragma unroll
  for (int mf=0;mf<2;mf++){
    #pragma unroll
    for (int nf=0;nf<4;nf++){
      int rr = mf*16 + (lane>>4)*4;
      int cc = nf*16 + (lane&15);
      #pragma unroll
      for (int g=0;g<4;g++) u.gbuf[w][rr+g][cc] = acc[mf][nf][g];
    }
  }
  __syncthreads();

  // pointwise LSTM update: 128 rows x 16 d = 2048 items, 8 per thread
  #pragma unroll
  for (int p=0;p<8;p++){
    int it = p*256 + tid;
    int row = it>>4, dj = it&15;
    int gr = row>>5, rr = row&31;
    const float* gb = &u.gbuf[gr][rr][dj*4];
    float gi = gb[0] + bc[n0p + dj*4 + 0];
    float gf = gb[1] + bc[n0p + dj*4 + 1];
    float gg = gb[2] + bc[n0p + dj*4 + 2];
    float go = gb[3] + bc[n0p + dj*4 + 3];
    int dg = (n0p>>2) + dj;
    size_t cidx = (size_t)ci*65536 + (size_t)row*512 + dg;
    float c = cbuf[cidx];
    float si = sigmoidf_(gi), sf = sigmoidf_(gf), so = sigmoidf_(go);
    float cn = sf*c + si*tanhf(gg);
    float h  = so*tanhf(cn);
    float mv = mask[(size_t)row*256 + t];
    cn *= mv; h *= mv;
    cbuf[cidx] = cn;
    H[(size_t)(t+1)*65536 + (size_t)row*512 + dg] = h;
  }
}

// ---------------- launch ---------------------------------------------------------
extern "C" void kernel_launch(void* const* d_in, const int* in_sizes, int n_in,
                              void* d_out, int out_size, void* d_ws, size_t ws_size,
                              hipStream_t stream)
{
  const float* feat0  = (const float*)d_in[0];
  const float* feat1  = (const float*)d_in[1];
  const float* fmask  = (const float*)d_in[2];
  const float* w_emb0 = (const float*)d_in[3];
  const float* b_emb0 = (const float*)d_in[4];
  const float* gamma0 = (const float*)d_in[5];
  const float* beta0  = (const float*)d_in[6];
  const float* w_emb1 = (const float*)d_in[7];
  const float* b_emb1 = (const float*)d_in[8];
  const float* gamma1 = (const float*)d_in[9];
  const float* beta1  = (const float*)d_in[10];
  const float* w_ih0  = (const float*)d_in[11];
  const float* w_hh0  = (const float*)d_in[12];
  const float* b_ih0  = (const float*)d_in[13];
  const float* b_hh0  = (const float*)d_in[14];
  const float* w_ih1  = (const float*)d_in[15];
  const float* w_hh1  = (const float*)d_in[16];
  const float* b_ih1  = (const float*)d_in[17];
  const float* b_hh1  = (const float*)d_in[18];
  const float* wg0    = (const float*)d_in[19];
  const float* bg0    = (const float*)d_in[20];
  const float* wg1    = (const float*)d_in[21];
  const float* bg1    = (const float*)d_in[22];
  const float* wf1    = (const float*)d_in[23];
  const float* wf2    = (const float*)d_in[24];
  const float* bf     = (const float*)d_in[25];
  float* out = (float*)d_out;

  float* ws = (float*)d_ws;
  float* e0    = ws;
  float* e1    = ws + 16777216ULL;
  float* H0    = ws + 33554432ULL;
  float* H1    = ws + 50397184ULL;
  float* cbuf  = ws + 67239936ULL;
  float* psum  = ws + 67371008ULL;
  float* psq   = ws + 67436544ULL;
  float* meanb = ws + 67502080ULL;
  float* scaleb= ws + 67502592ULL;
  u16* wr0hi = (u16*)(ws + 67503104ULL);
  u16* wr0lo = (u16*)(ws + 68551680ULL);
  u16* wr1hi = (u16*)(ws + 69600256ULL);
  u16* wr1lo = (u16*)(ws + 70648832ULL);
  float* bc0 = ws + 71697408ULL;
  float* bc1 = ws + 71699456ULL;
  u16* we0hi = (u16*)(ws + 71701504ULL);
  u16* we0lo = (u16*)(ws + 72225792ULL);
  u16* we1hi = (u16*)(ws + 72750080ULL);
  u16* we1lo = (u16*)(ws + 73012224ULL);
  u16* wg0hi = (u16*)(ws + 73274368ULL);
  u16* wg0lo = (u16*)(ws + 73405440ULL);
  u16* wg1hi = (u16*)(ws + 73536512ULL);
  u16* wg1lo = (u16*)(ws + 73667584ULL);
  u16* wf1hi = (u16*)(ws + 73798656ULL);
  u16* wf1lo = (u16*)(ws + 73929728ULL);
  u16* wf2hi = (u16*)(ws + 74060800ULL);
  u16* wf2lo = (u16*)(ws + 74191872ULL);

  // ---- weight splitting ----
  split_gates<<<dim3(2048), dim3(256), 0, stream>>>(w_ih0, w_hh0, b_ih0, b_hh0, wr0hi, wr0lo, bc0);
  split_gates<<<dim3(2048), dim3(256), 0, stream>>>(w_ih1, w_hh1, b_ih1, b_hh1, wr1hi, wr1lo, bc1);
  split_plain<<<dim3(4096), dim3(256), 0, stream>>>(w_emb0, we0hi, we0lo, 1048576);
  split_plain<<<dim3(2048), dim3(256), 0, stream>>>(w_emb1, we1hi, we1lo, 524288);
  split_plain<<<dim3(1024), dim3(256), 0, stream>>>(wg0, wg0hi, wg0lo, 262144);
  split_plain<<<dim3(1024), dim3(256), 0, stream>>>(wg1, wg1hi, wg1lo, 262144);
  split_plain<<<dim3(1024), dim3(256), 0, stream>>>(wf1, wf1hi, wf1lo, 262144);
  split_plain<<<dim3(1024), dim3(256), 0, stream>>>(wf2, wf2hi, wf2lo, 262144);

  // ---- embeddings (raw pre-BN), written t-major ----
  gemm_sp<0><<<dim3(1024), dim3(256), 0, stream>>>(feat0, we0hi, we0lo, nullptr, nullptr, nullptr, b_emb0, nullptr, e0, 2048);
  gemm_sp<0><<<dim3(1024), dim3(256), 0, stream>>>(feat1, we1hi, we1lo, nullptr, nullptr, nullptr, b_emb1, nullptr, e1, 1024);

  // ---- BN + ReLU ----
  bn_stats1<<<dim3(128), dim3(256), 0, stream>>>(e0, psum, psq);
  bn_stats2<<<dim3(1),   dim3(512), 0, stream>>>(psum, psq, meanb, scaleb);
  bn_apply <<<dim3(16384), dim3(256), 0, stream>>>(e0, meanb, scaleb, gamma0, beta0);
  bn_stats1<<<dim3(128), dim3(256), 0, stream>>>(e1, psum, psq);
  bn_stats2<<<dim3(1),   dim3(512), 0, stream>>>(psum, psq, meanb, scaleb);
  bn_apply <<<dim3(16384), dim3(256), 0, stream>>>(e1, meanb, scaleb, gamma1, beta1);

  // ---- scan ----
  init_state<<<dim3(256), dim3(256), 0, stream>>>(H0, H1, cbuf);
  for (int t=0; t<256; ++t){
    scan_step2<<<dim3(64), dim3(256), 0, stream>>>(e0, e1,
        wr0hi, wr0lo, wr1hi, wr1lo, bc0, bc1,
        fmask, H0, H1, cbuf, t);
  }

  // ---- gate0 = sigmoid(h1@wg0^T+bg0)*h0 -> e0 ; gate1 -> e1 ----
  gemm_sp<1><<<dim3(1024), dim3(256), 0, stream>>>(H1 + 65536, wg0hi, wg0lo, nullptr, nullptr, nullptr, bg0, H0 + 65536, e0, 512);
  gemm_sp<1><<<dim3(1024), dim3(256), 0, stream>>>(H0 + 65536, wg1hi, wg1lo, nullptr, nullptr, nullptr, bg1, H1 + 65536, e1, 512);

  // ---- out = tanh(g0@wf1^T + g1@wf2^T + bf), remapped to (B,T,D) ----
  gemm_sp<2><<<dim3(1024), dim3(256), 0, stream>>>(e0, wf1hi, wf1lo, e1, wf2hi, wf2lo, bf, nullptr, out, 512);
}

// Round 3
// 14451.872 us; speedup vs baseline: 1.6775x; 1.6775x over previous
//
#include <hip/hip_runtime.h>
#include <math.h>

// Dims: B=128, T=256, D=512, F0=2048, F1=1024, R=B*T=32768
//
// ws layout (BYTE offsets):
//  e0hi @ 0          33554432  bf16 planes, frag layout [t][ksub][rt][lane][8]
//  e0lo @ 33554432
//  e1hi @ 67108864
//  e1lo @ 100663296            (these 4 reused post-scan as g0hi/g0lo/g1hi/g1lo)
//  H0hi @ 134217728  33685504  [257 slots][ksub][rt][lane][8]
//  H0lo @ 167903232
//  H1hi @ 201588736
//  H1lo @ 235274240
//  cbuf @ 268959744  524288    f32 c-state both cells
//  psum @ 269484032  262144
//  psq  @ 269746176  262144
//  mean @ 270008320  2048
//  scl  @ 270010368  2048
//  bc0  @ 270012416  8192      permuted combined bias f32
//  bc1  @ 270020608  8192
//  wr0hi@ 270028800  4194304   W frag layout [64 ksub][64 ct][64 lane][8]
//  wr0lo@ 274223104
//  wr1hi@ 278417408
//  wr1lo@ 282611712
//  we0hi@ 286806016  2097152   row-major [512][2048] (emb GEMM stages via LDS)
//  we0lo@ 288903168
//  we1hi@ 291000320  1048576   row-major [512][1024]
//  we1lo@ 292048896
//  wg0hi@ 293097472  524288    frag layout [32][16][64][8]
//  wg0lo@ 293621760
//  wg1hi@ 294146048
//  wg1lo@ 294670336
//  wf1hi@ 295194624
//  wf1lo@ 295718912
//  wf2hi@ 296243200
//  wf2lo@ 296767488
//  end  @ 297291776  (283.5 MB; round-2 proved >= 297.3 MB available)
//  Y temp (fp32 32768x512 = 64MB) aliases H0hi..H0lo region (pre-scan only).

typedef short s16x8 __attribute__((ext_vector_type(8)));
typedef float f32x4 __attribute__((ext_vector_type(4)));
typedef float f32x16 __attribute__((ext_vector_type(16)));
typedef unsigned short u16;

__device__ __forceinline__ float sigmoidf_(float x){ return 1.0f/(1.0f+expf(-x)); }

__device__ __forceinline__ u16 f2bf(float x){
  unsigned int u = __float_as_uint(x);
  unsigned int r = u + 0x7fffu + ((u>>16)&1u);
  return (u16)(r>>16);
}
__device__ __forceinline__ float bf2f(u16 s){ return __uint_as_float(((unsigned int)s)<<16); }

// ============ weight prep ====================================================
// row-major split (emb weights)
__global__ __launch_bounds__(256) void split_plain(const float* __restrict__ src,
                                                   u16* __restrict__ hi, u16* __restrict__ lo, int n)
{
  int i = blockIdx.x*256 + threadIdx.x;
  if (i < n){
    float v = src[i];
    u16 h = f2bf(v);
    hi[i] = h;
    lo[i] = f2bf(v - bf2f(h));
  }
}

// frag-layout split for [N][K] row-major weights (N=512): off = ((ksub*(N/32)+ct)*64 + kh*32+(n&31))*8 + e
__global__ __launch_bounds__(256) void split_fragW(const float* __restrict__ src,
                                                   u16* __restrict__ hi, u16* __restrict__ lo,
                                                   int N, int K)
{
  int i = blockIdx.x*256 + threadIdx.x;
  if (i >= N*K) return;
  int n = i / K, k = i - n*K;
  float v = src[i];
  u16 h = f2bf(v), l2 = f2bf(v - bf2f(h));
  size_t off = ((((size_t)(k>>4)*(N/32) + (n>>5))*64) + ((k>>3)&1)*32 + (n&31))*8 + (k&7);
  hi[off] = h; lo[off] = l2;
}

// LSTM weights: permute rows (np = d*4+q from q*512+d), concat ih|hh along K=1024, frag layout
__global__ __launch_bounds__(256) void split_gates2(const float* __restrict__ wih,
                                                    const float* __restrict__ whh,
                                                    const float* __restrict__ bih,
                                                    const float* __restrict__ bhh,
                                                    u16* __restrict__ hi, u16* __restrict__ lo,
                                                    float* __restrict__ bc)
{
  int np = blockIdx.x;            // 0..2047
  int d = np>>2, q = np&3;
  int orow = q*512 + d;
  for (int k = threadIdx.x; k < 1024; k += 256){
    float v = (k < 512) ? wih[(size_t)orow*512 + k] : whh[(size_t)orow*512 + (k-512)];
    u16 h = f2bf(v), l2 = f2bf(v - bf2f(h));
    size_t off = (((size_t)(k>>4)*64 + (np>>5))*64 + ((k>>3)&1)*32 + (np&31))*8 + (k&7);
    hi[off] = h; lo[off] = l2;
  }
  if (threadIdx.x == 0) bc[np] = bih[orow] + bhh[orow];
}

// ============ emb GEMM (A fp32, in-kernel split; round-2 proven structure) ===
// C = A @ W^T + bias -> Y fp32 linear rows. A: MxK fp32, W planes row-major [512][K].
__global__ __launch_bounds__(256) void gemm_emb(
    const float* __restrict__ A, const u16* __restrict__ Whi, const u16* __restrict__ Wlo,
    const float* __restrict__ bias, float* __restrict__ out, int K)
{
  __shared__ u16 Ah[128][40];
  __shared__ u16 Al[128][40];
  __shared__ u16 Wh[128][40];
  __shared__ u16 Wl[128][40];

  int bx = blockIdx.x;
  int nt = bx & 3, mt = bx >> 2;
  int m0 = mt*128, n0 = nt*128;
  int tid = threadIdx.x, lane = tid & 63, w = tid >> 6;
  int wm = (w>>1)*64, wn = (w&1)*64;

  f32x4 acc[4][4];
  #pragma unroll
  for (int i=0;i<4;i++)
    #pragma unroll
    for (int j=0;j<4;j++) acc[i][j] = (f32x4){0.f,0.f,0.f,0.f};

  for (int k0=0; k0<K; k0+=32){
    #pragma unroll
    for (int p=0;p<4;p++){
      int fi = p*256 + tid;
      int r = fi>>3, c = fi&7;
      float4 v = *(const float4*)&A[(size_t)(m0+r)*K + k0 + c*4];
      u16 h0=f2bf(v.x), h1=f2bf(v.y), h2=f2bf(v.z), h3=f2bf(v.w);
      u16 l0=f2bf(v.x-bf2f(h0)), l1=f2bf(v.y-bf2f(h1)), l2=f2bf(v.z-bf2f(h2)), l3=f2bf(v.w-bf2f(h3));
      uint2 ph = { (unsigned)h0 | ((unsigned)h1<<16), (unsigned)h2 | ((unsigned)h3<<16) };
      uint2 pl = { (unsigned)l0 | ((unsigned)l1<<16), (unsigned)l2 | ((unsigned)l3<<16) };
      *(uint2*)&Ah[r][c*4] = ph;
      *(uint2*)&Al[r][c*4] = pl;
    }
    #pragma unroll
    for (int p=0;p<2;p++){
      int fi = p*256 + tid;
      int r = fi>>2, c = fi&3;
      uint4 vh = *(const uint4*)&Whi[(size_t)(n0+r)*K + k0 + c*8];
      uint4 vl = *(const uint4*)&Wlo[(size_t)(n0+r)*K + k0 + c*8];
      *(uint4*)&Wh[r][c*8] = vh;
      *(uint4*)&Wl[r][c*8] = vl;
    }
    __syncthreads();
    s16x8 ah[4], al[4];
    #pragma unroll
    for (int mf=0;mf<4;mf++){
      ah[mf] = *(const s16x8*)&Ah[wm + mf*16 + (lane&15)][(lane>>4)*8];
      al[mf] = *(const s16x8*)&Al[wm + mf*16 + (lane&15)][(lane>>4)*8];
    }
    #pragma unroll
    for (int nf=0;nf<4;nf++){
      s16x8 wh = *(const s16x8*)&Wh[wn + nf*16 + (lane&15)][(lane>>4)*8];
      s16x8 wl = *(const s16x8*)&Wl[wn + nf*16 + (lane&15)][(lane>>4)*8];
      #pragma unroll
      for (int mf=0;mf<4;mf++){
        acc[mf][nf] = __builtin_amdgcn_mfma_f32_16x16x32_bf16(ah[mf], wh, acc[mf][nf], 0,0,0);
        acc[mf][nf] = __builtin_amdgcn_mfma_f32_16x16x32_bf16(ah[mf], wl, acc[mf][nf], 0,0,0);
        acc[mf][nf] = __builtin_amdgcn_mfma_f32_16x16x32_bf16(al[mf], wh, acc[mf][nf], 0,0,0);
      }
    }
    __syncthreads();
  }
  #pragma unroll
  for (int mf=0;mf<4;mf++){
    #pragma unroll
    for (int nf=0;nf<4;nf++){
      int col = n0 + wn + nf*16 + (lane&15);
      int row0 = m0 + wm + mf*16 + (lane>>4)*4;
      float b = bias[col];
      #pragma unroll
      for (int g=0; g<4; ++g){
        out[(size_t)(row0+g)*512 + col] = acc[mf][nf][g] + b;
      }
    }
  }
}

// ============ BN ==============================================================
__global__ __launch_bounds__(256) void bn_stats1(const float* __restrict__ Y,
                                                 float* __restrict__ psum,
                                                 float* __restrict__ psq)
{
  int blk = blockIdx.x;
  int tid = threadIdx.x;
  const float* base = Y + (size_t)blk*256*512;
  float sx=0.f, sy=0.f, qx=0.f, qy=0.f;
  for (int r=0;r<256;r++){
    float2 v = *(const float2*)&base[(size_t)r*512 + tid*2];
    sx += v.x; sy += v.y; qx += v.x*v.x; qy += v.y*v.y;
  }
  psum[(size_t)blk*512 + tid*2]   = sx;
  psum[(size_t)blk*512 + tid*2+1] = sy;
  psq [(size_t)blk*512 + tid*2]   = qx;
  psq [(size_t)blk*512 + tid*2+1] = qy;
}

__global__ __launch_bounds__(512) void bn_stats2(const float* __restrict__ psum,
                                                 const float* __restrict__ psq,
                                                 float* __restrict__ mean,
                                                 float* __restrict__ scale)
{
  int c = threadIdx.x;
  float s=0.f, q=0.f;
  for (int b=0;b<128;b++){ s += psum[(size_t)b*512+c]; q += psq[(size_t)b*512+c]; }
  float mu = s * (1.0f/32768.0f);
  float var = q * (1.0f/32768.0f) - mu*mu;
  mean[c] = mu;
  scale[c] = rsqrtf(var + 1e-5f);
}

// BN+ReLU, split to hi/lo, write frag-layout e planes (row r=b*256+t -> slot t, row b)
__global__ __launch_bounds__(256) void bn_apply_split(const float* __restrict__ Y,
                                                      const float* __restrict__ mean,
                                                      const float* __restrict__ scale,
                                                      const float* __restrict__ gamma,
                                                      const float* __restrict__ beta,
                                                      u16* __restrict__ ehi, u16* __restrict__ elo)
{
  size_t idx = (size_t)blockIdx.x*256 + threadIdx.x;  // 32768*64
  int r = (int)(idx >> 6);
  int c0 = (int)(idx & 63) * 8;
  int b = r >> 8, t = r & 255;
  float4 v0 = *(const float4*)&Y[(size_t)r*512 + c0];
  float4 v1 = *(const float4*)&Y[(size_t)r*512 + c0 + 4];
  float vv[8] = {v0.x,v0.y,v0.z,v0.w,v1.x,v1.y,v1.z,v1.w};
  unsigned int hw[4], lw[4];
  #pragma unroll
  for (int u=0;u<8;u+=2){
    float xa = fmaxf((vv[u]  -mean[c0+u])  *scale[c0+u]  *gamma[c0+u]  +beta[c0+u],   0.f);
    float xb = fmaxf((vv[u+1]-mean[c0+u+1])*scale[c0+u+1]*gamma[c0+u+1]+beta[c0+u+1], 0.f);
    u16 ha = f2bf(xa), hb = f2bf(xb);
    u16 la = f2bf(xa - bf2f(ha)), lb = f2bf(xb - bf2f(hb));
    hw[u>>1] = (unsigned)ha | ((unsigned)hb<<16);
    lw[u>>1] = (unsigned)la | ((unsigned)lb<<16);
  }
  size_t off = (size_t)t*65536 + ((((size_t)(c0>>4)*4 + (b>>5))*64) + ((c0>>3)&1)*32 + (b&31))*8;
  uint4 ph = {hw[0],hw[1],hw[2],hw[3]};
  uint4 pl = {lw[0],lw[1],lw[2],lw[3]};
  *(uint4*)&ehi[off] = ph;
  *(uint4*)&elo[off] = pl;
}

// ============ init ============================================================
__global__ __launch_bounds__(256) void init2(u16* H0hi, u16* H0lo, u16* H1hi, u16* H1lo,
                                             float* cbuf)
{
  int i = blockIdx.x*256 + threadIdx.x;   // 32768 threads
  if (i < 8192){
    uint4 z = {0,0,0,0};
    ((uint4*)H0hi)[i] = z; ((uint4*)H0lo)[i] = z;
    ((uint4*)H1hi)[i] = z; ((uint4*)H1lo)[i] = z;
  }
  float4 zf = {0.f,0.f,0.f,0.f};
  ((float4*)cbuf)[i] = zf;
}

// ============ scan step: barrier-free, LDS-free MFMA =========================
// 64 blocks = [2 cells]x[32 n-strips of 64 permuted cols]; 4 waves, wave = 32 rows x 64 cols.
__global__ __launch_bounds__(256,1) void scan_step3(
    const u16* __restrict__ e0hi, const u16* __restrict__ e0lo,
    const u16* __restrict__ e1hi, const u16* __restrict__ e1lo,
    const u16* __restrict__ wr0hi, const u16* __restrict__ wr0lo,
    const u16* __restrict__ wr1hi, const u16* __restrict__ wr1lo,
    const float* __restrict__ bc0, const float* __restrict__ bc1,
    const float* __restrict__ mask,
    u16* __restrict__ H0hi, u16* __restrict__ H0lo,
    u16* __restrict__ H1hi, u16* __restrict__ H1lo,
    float* __restrict__ cbuf, int t)
{
  int bx = blockIdx.x;
  int ci = bx >> 5, nt = bx & 31;
  int n0p = nt * 64;

  const u16* ehi = ci ? e1hi : e0hi;
  const u16* elo = ci ? e1lo : e0lo;
  const u16* whi = ci ? wr1hi : wr0hi;
  const u16* wlo = ci ? wr1lo : wr0lo;
  const float* bc = ci ? bc1 : bc0;
  u16* Hhi = ci ? H1hi : H0hi;
  u16* Hlo = ci ? H1lo : H0lo;

  int tid = threadIdx.x, lane = tid & 63, w = tid >> 6;
  size_t eBase = (size_t)t*65536;

  f32x16 a0[2], a1[2], a2[2];
  #pragma unroll
  for (int c=0;c<2;c++){
    a0[c]=(f32x16)(0.f); a1[c]=(f32x16)(0.f); a2[c]=(f32x16)(0.f);
  }

  // k 0..511: e source
  #pragma unroll 2
  for (int kk=0; kk<32; ++kk){
    size_t aoff = eBase + (((size_t)kk*4 + w)*64 + lane)*8;
    s16x8 fah = *(const s16x8*)(ehi + aoff);
    s16x8 fal = *(const s16x8*)(elo + aoff);
    #pragma unroll
    for (int c=0;c<2;c++){
      size_t woff = (((size_t)kk*64 + nt*2 + c)*64 + lane)*8;
      s16x8 fwh = *(const s16x8*)(whi + woff);
      s16x8 fwl = *(const s16x8*)(wlo + woff);
      a0[c] = __builtin_amdgcn_mfma_f32_32x32x16_bf16(fah, fwh, a0[c], 0,0,0);
      a1[c] = __builtin_amdgcn_mfma_f32_32x32x16_bf16(fah, fwl, a1[c], 0,0,0);
      a2[c] = __builtin_amdgcn_mfma_f32_32x32x16_bf16(fal, fwh, a2[c], 0,0,0);
    }
  }
  // k 512..1023: h_{t-1} source (H slot t)
  #pragma unroll 2
  for (int kk=0; kk<32; ++kk){
    size_t aoff = eBase + (((size_t)kk*4 + w)*64 + lane)*8;
    s16x8 fah = *(const s16x8*)(Hhi + aoff);
    s16x8 fal = *(const s16x8*)(Hlo + aoff);
    #pragma unroll
    for (int c=0;c<2;c++){
      size_t woff = (((size_t)(kk+32)*64 + nt*2 + c)*64 + lane)*8;
      s16x8 fwh = *(const s16x8*)(whi + woff);
      s16x8 fwl = *(const s16x8*)(wlo + woff);
      a0[c] = __builtin_amdgcn_mfma_f32_32x32x16_bf16(fah, fwh, a0[c], 0,0,0);
      a1[c] = __builtin_amdgcn_mfma_f32_32x32x16_bf16(fah, fwl, a1[c], 0,0,0);
      a2[c] = __builtin_amdgcn_mfma_f32_32x32x16_bf16(fal, fwh, a2[c], 0,0,0);
    }
  }

  // epilogue: D frag: row_l = w*32 + (r&3)+8*(r>>2)+4*(lane>>5); col_l = c*32+(lane&31)
  int q = lane & 3;
  int colq = lane & 31;
  size_t hSlot = (size_t)(t+1)*65536;

  #pragma unroll
  for (int c=0;c<2;c++){
    f32x16 acc = a0[c] + a1[c] + a2[c];
    int col_l = c*32 + colq;          // permuted col within strip
    float bown = bc[n0p + col_l];
    int d = nt*16 + (col_l>>2);       // global d for this quad
    #pragma unroll
    for (int r=0;r<16;r++){
      float pre = acc[r] + bown;
      // own activation: q==2 is g-gate (tanh), else sigmoid
      float act = (q==2) ? tanhf(pre) : sigmoidf_(pre);
      float v1 = __shfl_xor(act, 1);
      float v2 = __shfl_xor(act, 2);
      float v3 = __shfl_xor(v1, 2);
      float gi = (q==0)? act : (q==1)? v1 : (q==2)? v2 : v3;
      float gf = (q==1)? act : (q==0)? v1 : (q==3)? v2 : v3;
      float gg = (q==2)? act : (q==3)? v1 : (q==0)? v2 : v3;
      float go = (q==3)? act : (q==2)? v1 : (q==1)? v2 : v3;
      int row = w*32 + (r&3) + 8*(r>>2) + 4*(lane>>5);
      size_t cidx = (size_t)ci*65536 + (size_t)row*512 + d;
      float cold = cbuf[cidx];
      float cn = gf*cold + gi*gg;
      float h  = go*tanhf(cn);
      float mv = mask[(size_t)row*256 + t];
      cn *= mv; h *= mv;
      if (q == (r&3)){
        cbuf[cidx] = cn;
        u16 hh = f2bf(h);
        u16 hl = f2bf(h - bf2f(hh));
        size_t hoff = hSlot + ((((size_t)(d>>4)*4 + w)*64) + ((d>>3)&1)*32 + (row&31))*8 + (d&7);
        Hhi[hoff] = hh;
        Hlo[hoff] = hl;
      }
    }
  }
}

// ============ frag-direct GEMM for gate / final ==============================
// 2048 blocks = 256 mt (t-slots) x 8 n-strips(64 cols). 4 waves, 32 rows x 64 cols.
// MODE 0 (gate): v = sigmoid(acc+bias)*other ; write out planes (frag layout, slot mt)
// MODE 1 (final): two A/W pairs; v = tanh(acc+bias); out fp32 at [b*256+t][col]
template<int MODE>
__global__ __launch_bounds__(256,1) void gemm_fr(
    const u16* __restrict__ Ahi,  const u16* __restrict__ Alo,
    const u16* __restrict__ A2hi, const u16* __restrict__ A2lo,
    const u16* __restrict__ Whi,  const u16* __restrict__ Wlo,
    const u16* __restrict__ W2hi, const u16* __restrict__ W2lo,
    const float* __restrict__ bias,
    const u16* __restrict__ OtHi, const u16* __restrict__ OtLo,
    u16* __restrict__ outHi, u16* __restrict__ outLo,
    float* __restrict__ outF)
{
  int bx = blockIdx.x;
  int nt = bx & 7, mt = bx >> 3;
  int n0 = nt*64;
  int tid = threadIdx.x, lane = tid & 63, w = tid >> 6;
  size_t aBase = (size_t)mt*65536;

  f32x16 a0[2], a1[2], a2[2];
  #pragma unroll
  for (int c=0;c<2;c++){
    a0[c]=(f32x16)(0.f); a1[c]=(f32x16)(0.f); a2[c]=(f32x16)(0.f);
  }

  const int npair = (MODE==1) ? 2 : 1;
  for (int pair=0; pair<npair; ++pair){
    const u16* ah = pair ? A2hi : Ahi;
    const u16* al = pair ? A2lo : Alo;
    const u16* wh = pair ? W2hi : Whi;
    const u16* wl = pair ? W2lo : Wlo;
    #pragma unroll 2
    for (int kk=0; kk<32; ++kk){
      size_t aoff = aBase + (((size_t)kk*4 + w)*64 + lane)*8;
      s16x8 fah = *(const s16x8*)(ah + aoff);
      s16x8 fal = *(const s16x8*)(al + aoff);
      #pragma unroll
      for (int c=0;c<2;c++){
        size_t woff = (((size_t)kk*16 + nt*2 + c)*64 + lane)*8;
        s16x8 fwh = *(const s16x8*)(wh + woff);
        s16x8 fwl = *(const s16x8*)(wl + woff);
        a0[c] = __builtin_amdgcn_mfma_f32_32x32x16_bf16(fah, fwh, a0[c], 0,0,0);
        a1[c] = __builtin_amdgcn_mfma_f32_32x32x16_bf16(fah, fwl, a1[c], 0,0,0);
        a2[c] = __builtin_amdgcn_mfma_f32_32x32x16_bf16(fal, fwh, a2[c], 0,0,0);
      }
    }
  }

  #pragma unroll
  for (int c=0;c<2;c++){
    f32x16 acc = a0[c] + a1[c] + a2[c];
    int col = n0 + c*32 + (lane&31);
    float b = bias[col];
    #pragma unroll
    for (int r=0;r<16;r++){
      int row = w*32 + (r&3) + 8*(r>>2) + 4*(lane>>5);
      float v = acc[r] + b;
      if (MODE==0){
        size_t foff = aBase + ((((size_t)(col>>4)*4 + w)*64) + ((col>>3)&1)*32 + (row&31))*8 + (col&7);
        float other = bf2f(OtHi[foff]) + bf2f(OtLo[foff]);
        v = sigmoidf_(v) * other;
        u16 hh = f2bf(v);
        u16 hl = f2bf(v - bf2f(hh));
        outHi[foff] = hh;
        outLo[foff] = hl;
      } else {
        v = tanhf(v);
        outF[((size_t)row*256 + mt)*512 + col] = v;
      }
    }
  }
}

// ============ launch ==========================================================
extern "C" void kernel_launch(void* const* d_in, const int* in_sizes, int n_in,
                              void* d_out, int out_size, void* d_ws, size_t ws_size,
                              hipStream_t stream)
{
  const float* feat0  = (const float*)d_in[0];
  const float* feat1  = (const float*)d_in[1];
  const float* fmask  = (const float*)d_in[2];
  const float* w_emb0 = (const float*)d_in[3];
  const float* b_emb0 = (const float*)d_in[4];
  const float* gamma0 = (const float*)d_in[5];
  const float* beta0  = (const float*)d_in[6];
  const float* w_emb1 = (const float*)d_in[7];
  const float* b_emb1 = (const float*)d_in[8];
  const float* gamma1 = (const float*)d_in[9];
  const float* beta1  = (const float*)d_in[10];
  const float* w_ih0  = (const float*)d_in[11];
  const float* w_hh0  = (const float*)d_in[12];
  const float* b_ih0  = (const float*)d_in[13];
  const float* b_hh0  = (const float*)d_in[14];
  const float* w_ih1  = (const float*)d_in[15];
  const float* w_hh1  = (const float*)d_in[16];
  const float* b_ih1  = (const float*)d_in[17];
  const float* b_hh1  = (const float*)d_in[18];
  const float* wg0    = (const float*)d_in[19];
  const float* bg0    = (const float*)d_in[20];
  const float* wg1    = (const float*)d_in[21];
  const float* bg1    = (const float*)d_in[22];
  const float* wf1    = (const float*)d_in[23];
  const float* wf2    = (const float*)d_in[24];
  const float* bf     = (const float*)d_in[25];
  float* out = (float*)d_out;

  char* ws = (char*)d_ws;
  u16* e0hi = (u16*)(ws + 0);
  u16* e0lo = (u16*)(ws + 33554432);
  u16* e1hi = (u16*)(ws + 67108864);
  u16* e1lo = (u16*)(ws + 100663296);
  u16* H0hi = (u16*)(ws + 134217728);
  u16* H0lo = (u16*)(ws + 167903232);
  u16* H1hi = (u16*)(ws + 201588736);
  u16* H1lo = (u16*)(ws + 235274240);
  float* cbuf  = (float*)(ws + 268959744);
  float* psum  = (float*)(ws + 269484032);
  float* psq   = (float*)(ws + 269746176);
  float* meanb = (float*)(ws + 270008320);
  float* scaleb= (float*)(ws + 270010368);
  float* bc0   = (float*)(ws + 270012416);
  float* bc1   = (float*)(ws + 270020608);
  u16* wr0hi = (u16*)(ws + 270028800);
  u16* wr0lo = (u16*)(ws + 274223104);
  u16* wr1hi = (u16*)(ws + 278417408);
  u16* wr1lo = (u16*)(ws + 282611712);
  u16* we0hi = (u16*)(ws + 286806016);
  u16* we0lo = (u16*)(ws + 288903168);
  u16* we1hi = (u16*)(ws + 291000320);
  u16* we1lo = (u16*)(ws + 292048896);
  u16* wg0hi = (u16*)(ws + 293097472);
  u16* wg0lo = (u16*)(ws + 293621760);
  u16* wg1hi = (u16*)(ws + 294146048);
  u16* wg1lo = (u16*)(ws + 294670336);
  u16* wf1hi = (u16*)(ws + 295194624);
  u16* wf1lo = (u16*)(ws + 295718912);
  u16* wf2hi = (u16*)(ws + 296243200);
  u16* wf2lo = (u16*)(ws + 296767488);
  float* Ytmp = (float*)(ws + 134217728);   // aliases H0hi/H0lo, pre-scan only

  // ---- weight prep ----
  split_gates2<<<dim3(2048), dim3(256), 0, stream>>>(w_ih0, w_hh0, b_ih0, b_hh0, wr0hi, wr0lo, bc0);
  split_gates2<<<dim3(2048), dim3(256), 0, stream>>>(w_ih1, w_hh1, b_ih1, b_hh1, wr1hi, wr1lo, bc1);
  split_plain<<<dim3(4096), dim3(256), 0, stream>>>(w_emb0, we0hi, we0lo, 1048576);
  split_plain<<<dim3(2048), dim3(256), 0, stream>>>(w_emb1, we1hi, we1lo, 524288);
  split_fragW<<<dim3(1024), dim3(256), 0, stream>>>(wg0, wg0hi, wg0lo, 512, 512);
  split_fragW<<<dim3(1024), dim3(256), 0, stream>>>(wg1, wg1hi, wg1lo, 512, 512);
  split_fragW<<<dim3(1024), dim3(256), 0, stream>>>(wf1, wf1hi, wf1lo, 512, 512);
  split_fragW<<<dim3(1024), dim3(256), 0, stream>>>(wf2, wf2hi, wf2lo, 512, 512);

  // ---- embeddings + BN (Y temp in H region) ----
  gemm_emb<<<dim3(1024), dim3(256), 0, stream>>>(feat0, we0hi, we0lo, b_emb0, Ytmp, 2048);
  bn_stats1<<<dim3(128), dim3(256), 0, stream>>>(Ytmp, psum, psq);
  bn_stats2<<<dim3(1),   dim3(512), 0, stream>>>(psum, psq, meanb, scaleb);
  bn_apply_split<<<dim3(8192), dim3(256), 0, stream>>>(Ytmp, meanb, scaleb, gamma0, beta0, e0hi, e0lo);

  gemm_emb<<<dim3(1024), dim3(256), 0, stream>>>(feat1, we1hi, we1lo, b_emb1, Ytmp, 1024);
  bn_stats1<<<dim3(128), dim3(256), 0, stream>>>(Ytmp, psum, psq);
  bn_stats2<<<dim3(1),   dim3(512), 0, stream>>>(psum, psq, meanb, scaleb);
  bn_apply_split<<<dim3(8192), dim3(256), 0, stream>>>(Ytmp, meanb, scaleb, gamma1, beta1, e1hi, e1lo);

  // ---- scan (zero-LDS, zero-barrier steps) ----
  init2<<<dim3(128), dim3(256), 0, stream>>>(H0hi, H0lo, H1hi, H1lo, cbuf);
  for (int t=0; t<256; ++t){
    scan_step3<<<dim3(64), dim3(256), 0, stream>>>(e0hi, e0lo, e1hi, e1lo,
        wr0hi, wr0lo, wr1hi, wr1lo, bc0, bc1, fmask,
        H0hi, H0lo, H1hi, H1lo, cbuf, t);
  }

  // ---- gate0 = sigmoid(h1@wg0^T+bg0)*h0 -> g0 planes (e0 region) ----
  gemm_fr<0><<<dim3(2048), dim3(256), 0, stream>>>(
      H1hi + 65536, H1lo + 65536, nullptr, nullptr,
      wg0hi, wg0lo, nullptr, nullptr, bg0,
      H0hi + 65536, H0lo + 65536, e0hi, e0lo, nullptr);
  // ---- gate1 = sigmoid(h0@wg1^T+bg1)*h1 -> g1 planes (e1 region) ----
  gemm_fr<0><<<dim3(2048), dim3(256), 0, stream>>>(
      H0hi + 65536, H0lo + 65536, nullptr, nullptr,
      wg1hi, wg1lo, nullptr, nullptr, bg1,
      H1hi + 65536, H1lo + 65536, e1hi, e1lo, nullptr);
  // ---- out = tanh(g0@wf1^T + g1@wf2^T + bf) ----
  gemm_fr<1><<<dim3(2048), dim3(256), 0, stream>>>(
      e0hi, e0lo, e1hi, e1lo,
      wf1hi, wf1lo, wf2hi, wf2lo, bf,
      nullptr, nullptr, nullptr, nullptr, out);
}